// Round 1
// baseline (377.823 us; speedup 1.0000x reference)
//
#include <hip/hip_runtime.h>
#include <hip/hip_bf16.h>

typedef unsigned short u16;
typedef __bf16 bf16x8 __attribute__((ext_vector_type(8)));
typedef float f32x4 __attribute__((ext_vector_type(4)));
typedef u16 u16x8 __attribute__((ext_vector_type(8)));

__device__ __forceinline__ u16 f2bf(float f) {
    __bf16 h = (__bf16)f;                 // RNE
    return __builtin_bit_cast(unsigned short, h);
}

// ---------------------------------------------------------------------------
// Kernel 1: ternary quantization. One block per output channel o.
// w is OIHW fp32 [256][256][3][3]. Writes wq[o][f][ci] bf16 (f = kh*3+kw),
// i.e. K-order = f*256 + ci, and alpha[o] fp32.
// Reductions in double so borderline w vs delta comparisons match the fp64
// numpy reference.
// ---------------------------------------------------------------------------
__global__ __launch_bounds__(256) void quant_kernel(
        const float* __restrict__ w, u16* __restrict__ wq,
        float* __restrict__ alpha) {
    int o = blockIdx.x;
    int t = threadIdx.x;          // t == ci (256 input channels)
    const float* wo = w + (size_t)o * 2304;
    float v[9];
    double asum = 0.0;
    #pragma unroll
    for (int i = 0; i < 9; ++i) { v[i] = wo[t * 9 + i]; asum += fabs((double)v[i]); }
    #pragma unroll
    for (int off = 32; off > 0; off >>= 1) asum += __shfl_down(asum, off, 64);
    __shared__ double red[4];
    int wv = t >> 6, lane = t & 63;
    if (lane == 0) red[wv] = asum;
    __syncthreads();
    double delta = 0.7 * ((red[0] + red[1] + red[2] + red[3]) / 2304.0);

    double msum = 0.0; int cnt = 0;
    #pragma unroll
    for (int i = 0; i < 9; ++i) {
        double f = (double)v[i];
        float tv = 0.f;
        if (f > delta) tv = 1.f;
        else if (f < -delta) tv = -1.f;
        if (tv != 0.f) { msum += fabs(f); cnt++; }
        wq[(size_t)o * 2304 + i * 256 + t] = f2bf(tv);
    }
    #pragma unroll
    for (int off = 32; off > 0; off >>= 1) {
        msum += __shfl_down(msum, off, 64);
        cnt  += __shfl_down(cnt,  off, 64);
    }
    __shared__ double red2[4];
    __shared__ int    redc[4];
    if (lane == 0) { red2[wv] = msum; redc[wv] = cnt; }
    __syncthreads();
    if (t == 0) {
        double ms = red2[0] + red2[1] + red2[2] + red2[3];
        int c = redc[0] + redc[1] + redc[2] + redc[3];
        alpha[o] = (float)(ms / (double)(c > 0 ? c : 1));
    }
}

// ---------------------------------------------------------------------------
// Kernel 2: x NCHW fp32 -> zero-padded NHWC bf16 [32][58][58][256].
// grid = (cchunk=4, hp=58, img=32), 256 threads. LDS transpose so both global
// read (along w) and global write (along c) are coalesced.
// ---------------------------------------------------------------------------
__global__ __launch_bounds__(256) void pad_kernel(
        const float* __restrict__ x, u16* __restrict__ xp) {
    int cc  = blockIdx.x;   // channel chunk of 64
    int hp  = blockIdx.y;   // padded row 0..57
    int img = blockIdx.z;
    int t = threadIdx.x;
    __shared__ u16 tile[64 * 57];   // [c][w], pad to 57 to break conflicts
    bool interior = (hp >= 1) && (hp <= 56);
    if (interior) {
        int h = hp - 1;
        for (int i = t; i < 64 * 56; i += 256) {
            int c = i / 56, wcol = i - c * 56;
            float f = x[(((size_t)img * 256 + cc * 64 + c) * 56 + h) * 56 + wcol];
            tile[c * 57 + wcol] = f2bf(f);
        }
    }
    __syncthreads();
    for (int i = t; i < 58 * 64; i += 256) {
        int wl = i >> 6, c = i & 63;
        u16 val = 0;   // bf16 zero
        if (interior && wl >= 1 && wl <= 56) val = tile[c * 57 + (wl - 1)];
        xp[(((size_t)img * 58 + hp) * 58 + wl) * 256 + cc * 64 + c] = val;
    }
}

// ---------------------------------------------------------------------------
// Kernel 3: implicit GEMM. D[o][sp] = sum_k Wq[o][k] * Xpatch[sp][k],
// k = f*256 + ci, f = kh*3+kw. 128x128 tile, BK=32, 4 waves of 4x4
// mfma_f32_16x16x32_bf16. Register-prefetch pipeline. Epilogue scales by
// alpha[o] and stores NCHW fp32.
// ---------------------------------------------------------------------------
#define LDK 40   // padded LDS row (bf16 elems): 80 B = 20 banks -> <=2-way

__global__ __launch_bounds__(256) void conv_gemm(
        const u16* __restrict__ Wq, const u16* __restrict__ Xp,
        const float* __restrict__ alpha, float* __restrict__ out) {
    __shared__ u16 lsA[128 * LDK];  // weights [o_local][k]
    __shared__ u16 lsB[128 * LDK];  // x patches [sp_local][k]

    int bid = blockIdx.x;
    int mt = bid & 1;          // o tile (0..1)
    unsigned nt = bid >> 1;    // sp tile (0..783)
    int o_base = mt * 128;
    unsigned sp_base = nt * 128u;

    int t = threadIdx.x;
    int lane = t & 63, wave = t >> 6;
    int wm = (wave >> 1) * 64, wn = (wave & 1) * 64;

    // -- staging assignment: row r = t>>2 (and r+64), 16B segment sub = t&3
    int r = t >> 2, sub = t & 3;
    const u16* aptr0 = Wq + (size_t)(o_base + r) * 2304 + sub * 8;
    const u16* aptr1 = aptr0 + (size_t)64 * 2304;

    unsigned sp0 = sp_base + (unsigned)r;
    unsigned sp1 = sp0 + 64u;
    unsigned img0 = sp0 / 3136u, rem0 = sp0 - img0 * 3136u;
    unsigned oh0 = rem0 / 56u,   ow0 = rem0 - oh0 * 56u;
    unsigned img1 = sp1 / 3136u, rem1 = sp1 - img1 * 3136u;
    unsigned oh1 = rem1 / 56u,   ow1 = rem1 - oh1 * 56u;
    const u16* bptr0 = Xp + ((size_t)(img0 * 58 + oh0) * 58 + ow0) * 256 + sub * 8;
    const u16* bptr1 = Xp + ((size_t)(img1 * 58 + oh1) * 58 + ow1) * 256 + sub * 8;

    f32x4 acc[4][4] = {};
    u16x8 ra0, ra1, rb0, rb1;

    // prologue: chunk 0 (f=0 -> kh=kw=0, c0=0)
    ra0 = *(const u16x8*)(aptr0);
    ra1 = *(const u16x8*)(aptr1);
    rb0 = *(const u16x8*)(bptr0);
    rb1 = *(const u16x8*)(bptr1);

    int row = lane & 15, quad = lane >> 4;
    int wA = r * LDK + sub * 8;
    int wA2 = (r + 64) * LDK + sub * 8;

    for (int kc = 0; kc < 72; ++kc) {
        if (kc) __syncthreads();
        *(u16x8*)&lsA[wA]  = ra0;
        *(u16x8*)&lsA[wA2] = ra1;
        *(u16x8*)&lsB[wA]  = rb0;
        *(u16x8*)&lsB[wA2] = rb1;
        __syncthreads();

        int kn = kc + 1;
        if (kn < 72) {
            int f  = kn >> 3;            // filter tap 0..8
            int c0 = (kn & 7) << 5;      // channel offset
            int kh = f / 3, kw = f - kh * 3;
            int aoff = kn * 32;
            int boff = (kh * 58 + kw) * 256 + c0;
            ra0 = *(const u16x8*)(aptr0 + aoff);
            ra1 = *(const u16x8*)(aptr1 + aoff);
            rb0 = *(const u16x8*)(bptr0 + boff);
            rb1 = *(const u16x8*)(bptr1 + boff);
        }

        bf16x8 af[4], bfr[4];
        #pragma unroll
        for (int i = 0; i < 4; ++i)
            af[i] = *(const bf16x8*)&lsA[(wm + i * 16 + row) * LDK + quad * 8];
        #pragma unroll
        for (int j = 0; j < 4; ++j)
            bfr[j] = *(const bf16x8*)&lsB[(wn + j * 16 + row) * LDK + quad * 8];
        #pragma unroll
        for (int i = 0; i < 4; ++i)
            #pragma unroll
            for (int j = 0; j < 4; ++j)
                acc[i][j] = __builtin_amdgcn_mfma_f32_16x16x32_bf16(
                                af[i], bfr[j], acc[i][j], 0, 0, 0);
    }

    // epilogue: C/D layout col=lane&15 (sp), row=quad*4+reg (o)
    int col = lane & 15;
    float al[4][4];
    #pragma unroll
    for (int i = 0; i < 4; ++i)
        #pragma unroll
        for (int rg = 0; rg < 4; ++rg)
            al[i][rg] = alpha[o_base + wm + i * 16 + quad * 4 + rg];

    #pragma unroll
    for (int j = 0; j < 4; ++j) {
        unsigned sp = sp_base + (unsigned)(wn + j * 16 + col);
        unsigned img = sp / 3136u;
        unsigned spi = sp - img * 3136u;
        float* ob = out + (size_t)img * 256 * 3136 + spi;
        #pragma unroll
        for (int i = 0; i < 4; ++i) {
            int o = o_base + wm + i * 16 + quad * 4;
            #pragma unroll
            for (int rg = 0; rg < 4; ++rg)
                ob[(size_t)(o + rg) * 3136] = acc[i][j][rg] * al[i][rg];
        }
    }
}

// ---------------------------------------------------------------------------
extern "C" void kernel_launch(void* const* d_in, const int* in_sizes, int n_in,
                              void* d_out, int out_size, void* d_ws, size_t ws_size,
                              hipStream_t stream) {
    const float* x = (const float*)d_in[0];
    const float* w = (const float*)d_in[1];
    float* out = (float*)d_out;

    char* ws = (char*)d_ws;
    // xpad: 32*58*58*256 bf16 = 55,115,776 B
    u16*   xp    = (u16*)ws;
    // wq:   256*2304 bf16 = 1,179,648 B
    u16*   wq    = (u16*)(ws + 55115776);
    float* alpha = (float*)(ws + 55115776 + 1179648);

    quant_kernel<<<256, 256, 0, stream>>>(w, wq, alpha);
    dim3 pg(4, 58, 32);
    pad_kernel<<<pg, 256, 0, stream>>>(x, xp);
    conv_gemm<<<784 * 2, 256, 0, stream>>>(wq, xp, alpha, out);
}